// Round 1
// baseline (601.595 us; speedup 1.0000x reference)
//
#include <hip/hip_runtime.h>

typedef unsigned short u16;
typedef __bf16 bf16x8 __attribute__((ext_vector_type(8)));
typedef float f32x4 __attribute__((ext_vector_type(4)));

#define DEV __device__ __forceinline__

DEV u16 f2bf(float f){
  unsigned u = __float_as_uint(f);
  u += 0x7fff + ((u >> 16) & 1);   // round-to-nearest-even
  return (u16)(u >> 16);
}
DEV float bf2f(u16 v){ return __uint_as_float(((unsigned)v) << 16); }

// async global->LDS, 16B per lane. LDS dest = wave-uniform base + lane*16.
DEV void gll16(const void* g, void* l){
  __builtin_amdgcn_global_load_lds(
    (__attribute__((address_space(1))) unsigned int*)(unsigned long long)g,
    (__attribute__((address_space(3))) unsigned int*)(unsigned int)(unsigned long long)l,
    16, 0, 0);
}

// ---------------------------------------------------------------------------
// C[M,N] = A[M,K] @ B[N,K]^T   (bf16 in, fp32 acc, fp32/bf16 out, opt bias)
// BM=WM*64, BN=WN*64, BK=32. 256 threads = 4 waves, wave grid WM x WN.
// Batched via blockIdx.z: off = (z/Z2)*s1 + (z%Z2)*s2 per operand.
// All M,N multiples of BM,BN; K multiple of 32 (caller guarantees).
// ---------------------------------------------------------------------------
template<int WM, int WN, int OBF, int BIAS>
__global__ __launch_bounds__(256) void gemm_bt(
    const u16* __restrict__ A, int lda, long sA1, long sA2,
    const u16* __restrict__ B, int ldb, long sB1, long sB2,
    void* __restrict__ Cv, int ldc, long sC1, long sC2,
    const float* __restrict__ bias,
    int M, int N, int K, int Z2)
{
  constexpr int BM = WM*64, BN = WN*64;
  constexpr int NW = WM*WN;
  constexpr int A_INSTS = BM/16, B_INSTS = BN/16;   // 1024B (16 rows) per inst
  constexpr int APW = A_INSTS/NW, BPW = B_INSTS/NW;
  __shared__ u16 sA[BM*32];
  __shared__ u16 sB[BN*32];
  const int tid  = threadIdx.x;
  const int wave = tid >> 6, lane = tid & 63;
  const int quad = lane >> 4, l16 = lane & 15;
  const int wm = wave % WM, wn = wave / WM;
  const long bm = blockIdx.y, bn = blockIdx.x;
  const int z  = blockIdx.z;
  const int z1 = z / Z2, z2 = z - z1*Z2;
  const u16* Ab = A + z1*sA1 + z2*sA2 + bm*BM*(long)lda;
  const u16* Bb = B + z1*sB1 + z2*sB2 + bn*BN*(long)ldb;

  f32x4 acc[4][4] = {};

  for (int k0 = 0; k0 < K; k0 += 32){
    __syncthreads();
#pragma unroll
    for (int j = 0; j < APW; j++){
      const int inst = wave*APW + j;
      const int o = inst*1024 + lane*16;          // byte offset in 64B-row tile
      const int row = o >> 6, colb = o & 63;
      gll16(Ab + (long)row*lda + k0 + (colb >> 1), &sA[inst*512]);
    }
#pragma unroll
    for (int j = 0; j < BPW; j++){
      const int inst = wave*BPW + j;
      const int o = inst*1024 + lane*16;
      const int row = o >> 6, colb = o & 63;
      gll16(Bb + (long)row*ldb + k0 + (colb >> 1), &sB[inst*512]);
    }
    __syncthreads();
    bf16x8 af[4], bfr[4];
#pragma unroll
    for (int mi = 0; mi < 4; mi++)
      af[mi] = *(const bf16x8*)&sA[(wm*64 + mi*16 + l16)*32 + quad*8];
#pragma unroll
    for (int ni = 0; ni < 4; ni++)
      bfr[ni] = *(const bf16x8*)&sB[(wn*64 + ni*16 + l16)*32 + quad*8];
#pragma unroll
    for (int mi = 0; mi < 4; mi++)
#pragma unroll
      for (int ni = 0; ni < 4; ni++)
        acc[mi][ni] = __builtin_amdgcn_mfma_f32_16x16x32_bf16(af[mi], bfr[ni], acc[mi][ni], 0, 0, 0);
  }

  // C/D layout: row = quad*4 + reg, col = lane&15 (verified m89/m91)
  const long crow0 = bm*BM + wm*64 + quad*4;
  const long ccol0 = bn*BN + wn*64 + l16;
  if (OBF){
    u16* Cp = (u16*)Cv + z1*sC1 + z2*sC2;
#pragma unroll
    for (int mi = 0; mi < 4; mi++)
#pragma unroll
      for (int ni = 0; ni < 4; ni++)
#pragma unroll
        for (int r = 0; r < 4; r++)
          Cp[(crow0 + mi*16 + r)*ldc + ccol0 + ni*16] = f2bf(acc[mi][ni][r]);
  } else {
    float* Cp = (float*)Cv + z1*sC1 + z2*sC2;
    float bv[4] = {0.f,0.f,0.f,0.f};
    if (BIAS){
#pragma unroll
      for (int ni = 0; ni < 4; ni++) bv[ni] = bias[ccol0 + ni*16];
    }
#pragma unroll
    for (int mi = 0; mi < 4; mi++)
#pragma unroll
      for (int ni = 0; ni < 4; ni++)
#pragma unroll
        for (int r = 0; r < 4; r++)
          Cp[(crow0 + mi*16 + r)*ldc + ccol0 + ni*16] = acc[mi][ni][r] + bv[ni];
  }
}

// fp32 -> bf16 convert with optional zero row-padding (row >= valid -> 0)
__global__ __launch_bounds__(256) void cvt_bf16(
    u16* __restrict__ dst, const float* __restrict__ src,
    long total, int rowlen, int valid_rows)
{
  long i = ((long)blockIdx.x*256 + threadIdx.x)*4;
  if (i >= total) return;
  long row = i / rowlen;
  ushort4 o;
  if (row < valid_rows){
    float4 v = *(const float4*)(src + i);
    o.x = f2bf(v.x); o.y = f2bf(v.y); o.z = f2bf(v.z); o.w = f2bf(v.w);
  } else { o.x = 0; o.y = 0; o.z = 0; o.w = 0; }
  *(ushort4*)(dst + i) = o;
}

// LayerNorm over rows of 512, fp32 in -> bf16 out; rows >= valid get zeros.
__global__ __launch_bounds__(256) void ln512_bf16(
    u16* __restrict__ out, const float* __restrict__ in,
    const float* __restrict__ gam, const float* __restrict__ bet, int valid_rows)
{
  const long row = blockIdx.x;
  const int tid = threadIdx.x;
  u16* op = out + row*512 + tid*2;
  if (row >= valid_rows){
    ushort2 z; z.x = 0; z.y = 0;
    *(ushort2*)op = z;
    return;                       // block-uniform branch
  }
  float2 x = *(const float2*)(in + row*512 + tid*2);
  float s  = x.x + x.y;
  float s2 = x.x*x.x + x.y*x.y;
#pragma unroll
  for (int m = 32; m; m >>= 1){ s += __shfl_xor(s, m, 64); s2 += __shfl_xor(s2, m, 64); }
  __shared__ float red[8];
  const int wave = tid >> 6, lane = tid & 63;
  if (lane == 0){ red[wave*2] = s; red[wave*2+1] = s2; }
  __syncthreads();
  float ts = red[0]+red[2]+red[4]+red[6];
  float t2 = red[1]+red[3]+red[5]+red[7];
  float mu  = ts * (1.f/512.f);
  float var = t2 * (1.f/512.f) - mu*mu;
  float rs  = rsqrtf(var + 1e-5f);
  float2 g2 = *(const float2*)(gam + tid*2);
  float2 b2 = *(const float2*)(bet + tid*2);
  ushort2 o;
  o.x = f2bf((x.x - mu)*rs*g2.x + b2.x);
  o.y = f2bf((x.y - mu)*rs*g2.y + b2.y);
  *(ushort2*)op = o;
}

// masked softmax over rows of 1024 (valid s < 1000), bf16 in-place, scale 1/8
__global__ __launch_bounds__(256) void softmax_rows(u16* __restrict__ P)
{
  const long row = blockIdx.x;
  u16* ptr = P + row*1024;
  const int tid = threadIdx.x;
  const int wave = tid >> 6, lane = tid & 63;
  ushort4 raw = *(const ushort4*)(ptr + tid*4);
  const int s0 = tid*4;
  float v0 = bf2f(raw.x)*0.125f, v1 = bf2f(raw.y)*0.125f;
  float v2 = bf2f(raw.z)*0.125f, v3 = bf2f(raw.w)*0.125f;
  float mx = -3e38f;
  if (s0+0 < 1000) mx = fmaxf(mx, v0);
  if (s0+1 < 1000) mx = fmaxf(mx, v1);
  if (s0+2 < 1000) mx = fmaxf(mx, v2);
  if (s0+3 < 1000) mx = fmaxf(mx, v3);
#pragma unroll
  for (int m = 32; m; m >>= 1) mx = fmaxf(mx, __shfl_xor(mx, m, 64));
  __shared__ float red[4];
  if (lane == 0) red[wave] = mx;
  __syncthreads();
  float M = fmaxf(fmaxf(red[0], red[1]), fmaxf(red[2], red[3]));
  __syncthreads();
  float e0 = (s0+0 < 1000) ? __expf(v0 - M) : 0.f;
  float e1 = (s0+1 < 1000) ? __expf(v1 - M) : 0.f;
  float e2 = (s0+2 < 1000) ? __expf(v2 - M) : 0.f;
  float e3 = (s0+3 < 1000) ? __expf(v3 - M) : 0.f;
  float sm = e0 + e1 + e2 + e3;
#pragma unroll
  for (int m = 32; m; m >>= 1) sm += __shfl_xor(sm, m, 64);
  if (lane == 0) red[wave] = sm;
  __syncthreads();
  float inv = 1.f / (red[0]+red[1]+red[2]+red[3]);
  ushort4 o;
  o.x = f2bf(e0*inv); o.y = f2bf(e1*inv); o.z = f2bf(e2*inv); o.w = f2bf(e3*inv);
  *(ushort4*)(ptr + tid*4) = o;
}

// kv (1024 x 2048 fp32, [s][h*128 + (k:0..63 | v:64..127)]) ->
//   k_bf[h][s][e] (bf16) and vT_bf[h][e][s] (bf16, transposed via LDS)
__global__ __launch_bounds__(256) void split_kv(
    const float* __restrict__ kv, u16* __restrict__ kbf, u16* __restrict__ vT)
{
  const int h  = blockIdx.x;      // 16
  const int sc = blockIdx.y;      // 16 chunks of 64 s
  const int s0 = sc*64;
  __shared__ u16 tile[64][65];
  const int e  = threadIdx.x & 63;
  const int sg = threadIdx.x >> 6;
#pragma unroll
  for (int i = 0; i < 16; i++){
    const int sl = i*4 + sg;
    const long s = s0 + sl;
    float kvl = kv[s*2048 + h*128 + e];
    float vvl = kv[s*2048 + h*128 + 64 + e];
    kbf[((long)h*1024 + s)*64 + e] = f2bf(kvl);
    tile[sl][e] = f2bf(vvl);
  }
  __syncthreads();
#pragma unroll
  for (int i = 0; i < 16; i++){
    const int er = i*4 + sg;
    vT[(long)h*65536 + (long)er*1024 + s0 + e] = tile[e][er];
  }
}

extern "C" void kernel_launch(void* const* d_in, const int* in_sizes, int n_in,
                              void* d_out, int out_size, void* d_ws, size_t ws_size,
                              hipStream_t stream)
{
  const float* te   = (const float*)d_in[0];
  const float* se   = (const float*)d_in[1];
  // d_in[2] (value_embedding) is unused by the reference
  const float* qaw  = (const float*)d_in[3];
  const float* qlg  = (const float*)d_in[4];
  const float* qlb  = (const float*)d_in[5];
  const float* qbw  = (const float*)d_in[6];
  const float* kvaw = (const float*)d_in[7];
  const float* kvlg = (const float*)d_in[8];
  const float* kvlb = (const float*)d_in[9];
  const float* kvbw = (const float*)d_in[10];
  const float* outw = (const float*)d_in[11];
  const float* outb = (const float*)d_in[12];
  float* out = (float*)d_out;

  char* ws = (char*)d_ws;
  size_t off = 0;
  auto alloc = [&](size_t bytes){ void* p = ws + off; off += (bytes + 255) & ~255ULL; return p; };
  u16*   te_bf   = (u16*)  alloc(4096UL*1024*2);
  u16*   qa_bf   = (u16*)  alloc(512UL*1024*2);
  u16*   qb_bf   = (u16*)  alloc(1024UL*512*2);
  u16*   kva_bf  = (u16*)  alloc(512UL*4096*2);
  u16*   kvb_bf  = (u16*)  alloc(2048UL*512*2);
  u16*   outw_bf = (u16*)  alloc(4096UL*1024*2);
  u16*   se_bf   = (u16*)  alloc(1024UL*4096*2);   // padded 1000->1024 rows
  float* qlat    = (float*)alloc(4096UL*512*4);
  u16*   qln_bf  = (u16*)  alloc(4096UL*512*2);
  u16*   q_bf    = (u16*)  alloc(4096UL*1024*2);
  float* ckv     = (float*)alloc(1024UL*512*4);
  u16*   ckv_bf  = (u16*)  alloc(1024UL*512*2);
  float* kvf     = (float*)alloc(1024UL*2048*4);
  u16*   k_bf    = (u16*)  alloc(16UL*1024*64*2);
  u16*   vT_bf   = (u16*)  alloc(16UL*64*1024*2);
  u16*   attn_bf = (u16*)  alloc(4096UL*1024*2);
  u16*   scores  = (u16*)  alloc(16UL*1024*1024*2); // per-b, reused across b
  (void)ws_size; (void)in_sizes; (void)n_in; (void)out_size;

  auto cvt = [&](u16* dst, const float* src, long total, int rowlen, int valid){
    int blocks = (int)((total/4 + 255)/256);
    cvt_bf16<<<blocks, 256, 0, stream>>>(dst, src, total, rowlen, valid);
  };
  cvt(te_bf,   te,   4096L*1024, 1024, 4096);
  cvt(qa_bf,   qaw,  512L*1024,  1024, 512);
  cvt(qb_bf,   qbw,  1024L*512,  512,  1024);
  cvt(kva_bf,  kvaw, 512L*4096,  4096, 512);
  cvt(kvb_bf,  kvbw, 2048L*512,  512,  2048);
  cvt(outw_bf, outw, 4096L*1024, 1024, 4096);
  cvt(se_bf,   se,   1024L*4096, 4096, 1000);      // zero-pad rows 1000..1023

  // G1: q_lat = te @ q_a_w^T   (4096 x 512 x 1024), fp32 out
  gemm_bt<2,2,0,0><<<dim3(4, 32, 1), 256, 0, stream>>>(
      te_bf, 1024, 0,0, qa_bf, 1024, 0,0, qlat, 512, 0,0, nullptr, 4096, 512, 1024, 1);
  ln512_bf16<<<4096, 256, 0, stream>>>(qln_bf, qlat, qlg, qlb, 4096);
  // G2: q = ln(q_lat) @ q_b_w^T  (4096 x 1024 x 512), bf16 out
  gemm_bt<2,2,1,0><<<dim3(8, 32, 1), 256, 0, stream>>>(
      qln_bf, 512, 0,0, qb_bf, 512, 0,0, q_bf, 1024, 0,0, nullptr, 4096, 1024, 512, 1);
  // G3: ckv_lat = se @ kv_a_w^T  (1024 x 512 x 4096), fp32 out
  gemm_bt<2,2,0,0><<<dim3(4, 8, 1), 256, 0, stream>>>(
      se_bf, 4096, 0,0, kva_bf, 4096, 0,0, ckv, 512, 0,0, nullptr, 1024, 512, 4096, 1);
  ln512_bf16<<<1024, 256, 0, stream>>>(ckv_bf, ckv, kvlg, kvlb, 1000); // zero rows >= 1000
  // G4: kv = ckv @ kv_b_w^T  (1024 x 2048 x 512), fp32 out
  gemm_bt<2,2,0,0><<<dim3(16, 8, 1), 256, 0, stream>>>(
      ckv_bf, 512, 0,0, kvb_bf, 512, 0,0, kvf, 2048, 0,0, nullptr, 1024, 2048, 512, 1);
  split_kv<<<dim3(16, 16), 256, 0, stream>>>(kvf, k_bf, vT_bf);

  for (int b = 0; b < 4; b++){
    // scores[h][l][s] = q[b,l,h,:] . k[h,s,:]   (batched over h: z2 = h)
    gemm_bt<2,2,1,0><<<dim3(8, 8, 16), 256, 0, stream>>>(
        q_bf + (long)b*1024*1024, 1024, 0, 64,
        k_bf, 64, 0, 65536,
        scores, 1024, 0, 1048576,
        nullptr, 1024, 1024, 64, 16);
    softmax_rows<<<16*1024, 256, 0, stream>>>(scores);
    // attn[b,l,h,e] = sum_s P[h][l][s] * vT[h][e][s]
    gemm_bt<4,1,1,0><<<dim3(1, 4, 16), 256, 0, stream>>>(
        scores, 1024, 0, 1048576,
        vT_bf, 1024, 0, 65536,
        attn_bf + (long)b*1024*1024, 1024, 0, 64,
        nullptr, 1024, 64, 1024, 16);
  }

  // G7: out = attn @ out_w^T + out_b  (4096 x 4096 x 1024), fp32 out + bias
  gemm_bt<2,2,0,1><<<dim3(32, 32, 1), 256, 0, stream>>>(
      attn_bf, 1024, 0,0, outw_bf, 1024, 0,0, out, 4096, 0,0, outb, 4096, 4096, 1024, 1);
}

// Round 2
// 445.843 us; speedup vs baseline: 1.3493x; 1.3493x over previous
//
#include <hip/hip_runtime.h>

typedef unsigned short u16;
typedef __bf16 bf16x8 __attribute__((ext_vector_type(8)));
typedef float f32x4 __attribute__((ext_vector_type(4)));

#define DEV __device__ __forceinline__

DEV u16 f2bf(float f){
  unsigned u = __float_as_uint(f);
  u += 0x7fff + ((u >> 16) & 1);   // round-to-nearest-even
  return (u16)(u >> 16);
}
DEV float bf2f(u16 v){ return __uint_as_float(((unsigned)v) << 16); }

// async global->LDS, 16B per lane. LDS dest = wave-uniform base + lane*16.
DEV void gll16(const void* g, void* l){
  __builtin_amdgcn_global_load_lds(
    (__attribute__((address_space(1))) unsigned int*)(unsigned long long)g,
    (__attribute__((address_space(3))) unsigned int*)(unsigned int)(unsigned long long)l,
    16, 0, 0);
}

// ---------------------------------------------------------------------------
// C[M,N] = A[M,K] @ B[N,K]^T   (bf16 in, fp32 acc, fp32/bf16 out, opt bias)
// BM=WM*64, BN=WN*64, BK=32. NW=WM*WN waves (NW*64 threads).
// Batched via blockIdx.z: off = (z/Z2)*s1 + (z%Z2)*s2 per operand.
// Split-K usage: z1 = split idx, sA1/sB1 = k-chunk offset (elements),
// sC1 = partial-buffer stride, K = chunk length.
// ---------------------------------------------------------------------------
template<int WM, int WN, int OBF, int BIAS>
__global__ __launch_bounds__(256) void gemm_bt(
    const u16* __restrict__ A, int lda, long sA1, long sA2,
    const u16* __restrict__ B, int ldb, long sB1, long sB2,
    void* __restrict__ Cv, int ldc, long sC1, long sC2,
    const float* __restrict__ bias,
    int M, int N, int K, int Z2)
{
  constexpr int BM = WM*64, BN = WN*64;
  constexpr int NW = WM*WN;
  constexpr int A_INSTS = BM/16, B_INSTS = BN/16;   // 1024B (16 rows) per inst
  constexpr int APW = A_INSTS/NW, BPW = B_INSTS/NW;
  __shared__ u16 sA[BM*32];
  __shared__ u16 sB[BN*32];
  const int tid  = threadIdx.x;
  const int wave = tid >> 6, lane = tid & 63;
  const int quad = lane >> 4, l16 = lane & 15;
  const int wm = wave % WM, wn = wave / WM;
  const long bm = blockIdx.y, bn = blockIdx.x;
  const int z  = blockIdx.z;
  const int z1 = z / Z2, z2 = z - z1*Z2;
  const u16* Ab = A + z1*sA1 + z2*sA2 + bm*BM*(long)lda;
  const u16* Bb = B + z1*sB1 + z2*sB2 + bn*BN*(long)ldb;

  f32x4 acc[4][4] = {};

  for (int k0 = 0; k0 < K; k0 += 32){
    __syncthreads();
#pragma unroll
    for (int j = 0; j < APW; j++){
      const int inst = wave*APW + j;
      const int o = inst*1024 + lane*16;          // byte offset in 64B-row tile
      const int row = o >> 6, colb = o & 63;
      gll16(Ab + (long)row*lda + k0 + (colb >> 1), &sA[inst*512]);
    }
#pragma unroll
    for (int j = 0; j < BPW; j++){
      const int inst = wave*BPW + j;
      const int o = inst*1024 + lane*16;
      const int row = o >> 6, colb = o & 63;
      gll16(Bb + (long)row*ldb + k0 + (colb >> 1), &sB[inst*512]);
    }
    __syncthreads();
    bf16x8 af[4], bfr[4];
#pragma unroll
    for (int mi = 0; mi < 4; mi++)
      af[mi] = *(const bf16x8*)&sA[(wm*64 + mi*16 + l16)*32 + quad*8];
#pragma unroll
    for (int ni = 0; ni < 4; ni++)
      bfr[ni] = *(const bf16x8*)&sB[(wn*64 + ni*16 + l16)*32 + quad*8];
#pragma unroll
    for (int mi = 0; mi < 4; mi++)
#pragma unroll
      for (int ni = 0; ni < 4; ni++)
        acc[mi][ni] = __builtin_amdgcn_mfma_f32_16x16x32_bf16(af[mi], bfr[ni], acc[mi][ni], 0, 0, 0);
  }

  // C/D layout: row = quad*4 + reg, col = lane&15 (verified m89/m91)
  const long crow0 = bm*BM + wm*64 + quad*4;
  const long ccol0 = bn*BN + wn*64 + l16;
  if (OBF){
    u16* Cp = (u16*)Cv + z1*sC1 + z2*sC2;
#pragma unroll
    for (int mi = 0; mi < 4; mi++)
#pragma unroll
      for (int ni = 0; ni < 4; ni++)
#pragma unroll
        for (int r = 0; r < 4; r++)
          Cp[(crow0 + mi*16 + r)*ldc + ccol0 + ni*16] = f2bf(acc[mi][ni][r]);
  } else {
    float* Cp = (float*)Cv + z1*sC1 + z2*sC2;
    float bv[4] = {0.f,0.f,0.f,0.f};
    if (BIAS){
#pragma unroll
      for (int ni = 0; ni < 4; ni++) bv[ni] = bias[ccol0 + ni*16];
    }
#pragma unroll
    for (int mi = 0; mi < 4; mi++)
#pragma unroll
      for (int ni = 0; ni < 4; ni++)
#pragma unroll
        for (int r = 0; r < 4; r++)
          Cp[(crow0 + mi*16 + r)*ldc + ccol0 + ni*16] = acc[mi][ni][r] + bv[ni];
  }
}

// fp32 -> bf16 convert with optional zero row-padding (row >= valid -> 0)
__global__ __launch_bounds__(256) void cvt_bf16(
    u16* __restrict__ dst, const float* __restrict__ src,
    long total, int rowlen, int valid_rows)
{
  long i = ((long)blockIdx.x*256 + threadIdx.x)*4;
  if (i >= total) return;
  long row = i / rowlen;
  ushort4 o;
  if (row < valid_rows){
    float4 v = *(const float4*)(src + i);
    o.x = f2bf(v.x); o.y = f2bf(v.y); o.z = f2bf(v.z); o.w = f2bf(v.w);
  } else { o.x = 0; o.y = 0; o.z = 0; o.w = 0; }
  *(ushort4*)(dst + i) = o;
}

// LayerNorm over rows of 512 with split-K reduction: sums `nparts` fp32
// partials (stride pstride), then LN -> bf16. rows >= valid get zeros.
__global__ __launch_bounds__(256) void ln512red(
    u16* __restrict__ out, const float* __restrict__ in, long pstride, int nparts,
    const float* __restrict__ gam, const float* __restrict__ bet, int valid_rows)
{
  const long row = blockIdx.x;
  const int tid = threadIdx.x;
  u16* op = out + row*512 + tid*2;
  if (row >= valid_rows){
    ushort2 z; z.x = 0; z.y = 0;
    *(ushort2*)op = z;
    return;                       // block-uniform branch
  }
  float2 x; x.x = 0.f; x.y = 0.f;
  for (int p = 0; p < nparts; p++){
    float2 v = *(const float2*)(in + p*pstride + row*512 + tid*2);
    x.x += v.x; x.y += v.y;
  }
  float s  = x.x + x.y;
  float s2 = x.x*x.x + x.y*x.y;
#pragma unroll
  for (int m = 32; m; m >>= 1){ s += __shfl_xor(s, m, 64); s2 += __shfl_xor(s2, m, 64); }
  __shared__ float red[8];
  const int wave = tid >> 6, lane = tid & 63;
  if (lane == 0){ red[wave*2] = s; red[wave*2+1] = s2; }
  __syncthreads();
  float ts = red[0]+red[2]+red[4]+red[6];
  float t2 = red[1]+red[3]+red[5]+red[7];
  float mu  = ts * (1.f/512.f);
  float var = t2 * (1.f/512.f) - mu*mu;
  float rs  = rsqrtf(var + 1e-5f);
  float2 g2 = *(const float2*)(gam + tid*2);
  float2 b2 = *(const float2*)(bet + tid*2);
  ushort2 o;
  o.x = f2bf((x.x - mu)*rs*g2.x + b2.x);
  o.y = f2bf((x.y - mu)*rs*g2.y + b2.y);
  *(ushort2*)op = o;
}

// masked softmax over rows of 1024 (valid s < 1000), bf16 in-place, scale 1/8
__global__ __launch_bounds__(256) void softmax_rows(u16* __restrict__ P)
{
  const long row = blockIdx.x;
  u16* ptr = P + row*1024;
  const int tid = threadIdx.x;
  const int wave = tid >> 6, lane = tid & 63;
  ushort4 raw = *(const ushort4*)(ptr + tid*4);
  const int s0 = tid*4;
  float v0 = bf2f(raw.x)*0.125f, v1 = bf2f(raw.y)*0.125f;
  float v2 = bf2f(raw.z)*0.125f, v3 = bf2f(raw.w)*0.125f;
  float mx = -3e38f;
  if (s0+0 < 1000) mx = fmaxf(mx, v0);
  if (s0+1 < 1000) mx = fmaxf(mx, v1);
  if (s0+2 < 1000) mx = fmaxf(mx, v2);
  if (s0+3 < 1000) mx = fmaxf(mx, v3);
#pragma unroll
  for (int m = 32; m; m >>= 1) mx = fmaxf(mx, __shfl_xor(mx, m, 64));
  __shared__ float red[4];
  if (lane == 0) red[wave] = mx;
  __syncthreads();
  float M = fmaxf(fmaxf(red[0], red[1]), fmaxf(red[2], red[3]));
  __syncthreads();
  float e0 = (s0+0 < 1000) ? __expf(v0 - M) : 0.f;
  float e1 = (s0+1 < 1000) ? __expf(v1 - M) : 0.f;
  float e2 = (s0+2 < 1000) ? __expf(v2 - M) : 0.f;
  float e3 = (s0+3 < 1000) ? __expf(v3 - M) : 0.f;
  float sm = e0 + e1 + e2 + e3;
#pragma unroll
  for (int m = 32; m; m >>= 1) sm += __shfl_xor(sm, m, 64);
  if (lane == 0) red[wave] = sm;
  __syncthreads();
  float inv = 1.f / (red[0]+red[1]+red[2]+red[3]);
  ushort4 o;
  o.x = f2bf(e0*inv); o.y = f2bf(e1*inv); o.z = f2bf(e2*inv); o.w = f2bf(e3*inv);
  *(ushort4*)(ptr + tid*4) = o;
}

// kv partials (2 x [1024 x 2048] fp32, [s][h*128 + (k:0..63 | v:64..127)]) ->
//   k_bf[h][s][e] (bf16) and vT_bf[h][e][s] (bf16, transposed via LDS)
__global__ __launch_bounds__(256) void split_kv(
    const float* __restrict__ kv, u16* __restrict__ kbf, u16* __restrict__ vT)
{
  const int h  = blockIdx.x;      // 16
  const int sc = blockIdx.y;      // 16 chunks of 64 s
  const int s0 = sc*64;
  const long PST = 1024L*2048;
  __shared__ u16 tile[64][65];
  const int e  = threadIdx.x & 63;
  const int sg = threadIdx.x >> 6;
#pragma unroll
  for (int i = 0; i < 16; i++){
    const int sl = i*4 + sg;
    const long s = s0 + sl;
    float kvl = kv[s*2048 + h*128 + e]      + kv[PST + s*2048 + h*128 + e];
    float vvl = kv[s*2048 + h*128 + 64 + e] + kv[PST + s*2048 + h*128 + 64 + e];
    kbf[((long)h*1024 + s)*64 + e] = f2bf(kvl);
    tile[sl][e] = f2bf(vvl);
  }
  __syncthreads();
#pragma unroll
  for (int i = 0; i < 16; i++){
    const int er = i*4 + sg;
    vT[(long)h*65536 + (long)er*1024 + s0 + e] = tile[e][er];
  }
}

extern "C" void kernel_launch(void* const* d_in, const int* in_sizes, int n_in,
                              void* d_out, int out_size, void* d_ws, size_t ws_size,
                              hipStream_t stream)
{
  const float* te   = (const float*)d_in[0];
  const float* se   = (const float*)d_in[1];
  // d_in[2] (value_embedding) is unused by the reference
  const float* qaw  = (const float*)d_in[3];
  const float* qlg  = (const float*)d_in[4];
  const float* qlb  = (const float*)d_in[5];
  const float* qbw  = (const float*)d_in[6];
  const float* kvaw = (const float*)d_in[7];
  const float* kvlg = (const float*)d_in[8];
  const float* kvlb = (const float*)d_in[9];
  const float* kvbw = (const float*)d_in[10];
  const float* outw = (const float*)d_in[11];
  const float* outb = (const float*)d_in[12];
  float* out = (float*)d_out;
  (void)ws_size; (void)in_sizes; (void)n_in; (void)out_size;

  char* ws = (char*)d_ws;
  const size_t MB = 1024*1024;
  // Region R0 (0..64MB): early transients, all dead before attention.
  // scores (64MB, bf16 [h(8)][bl(4096)][s(1024)] per h-half) aliases R0.
  u16*   te_bf  = (u16*)  (ws + 0*MB);    // 8MB   cvt -> G1
  u16*   se_bf  = (u16*)  (ws + 8*MB);    // 8MB   cvt -> G3
  float* qlat   = (float*)(ws + 16*MB);   // 16MB  G1 partials (2) -> ln
  float* ckvp   = (float*)(ws + 32*MB);   // 16MB  G3 partials (8) -> ln
  float* kvf    = (float*)(ws + 48*MB);   // 16MB  G4 partials (2) -> split_kv
  u16*   scores = (u16*)  (ws + 0*MB);    // 64MB  aliases all of the above
  // Region R1 (64MB..): persistent
  u16*   qa_bf   = (u16*)(ws + 64*MB);    // 1MB
  u16*   qb_bf   = (u16*)(ws + 65*MB);    // 1MB
  u16*   kva_bf  = (u16*)(ws + 66*MB);    // 4MB
  u16*   kvb_bf  = (u16*)(ws + 70*MB);    // 2MB
  u16*   outw_bf = (u16*)(ws + 72*MB);    // 8MB
  u16*   qln_bf  = (u16*)(ws + 80*MB);    // 4MB
  u16*   q_bf    = (u16*)(ws + 84*MB);    // 8MB
  u16*   ckv_bf  = (u16*)(ws + 92*MB);    // 1MB
  u16*   k_bf    = (u16*)(ws + 93*MB);    // 2MB
  u16*   vT_bf   = (u16*)(ws + 95*MB);    // 2MB
  u16*   attn_bf = (u16*)(ws + 97*MB);    // 8MB   -> 105MB total

  auto cvt = [&](u16* dst, const float* src, long total, int rowlen, int valid){
    int blocks = (int)((total/4 + 255)/256);
    cvt_bf16<<<blocks, 256, 0, stream>>>(dst, src, total, rowlen, valid);
  };
  cvt(te_bf,   te,   4096L*1024, 1024, 4096);
  cvt(qa_bf,   qaw,  512L*1024,  1024, 512);
  cvt(qb_bf,   qbw,  1024L*512,  512,  1024);
  cvt(kva_bf,  kvaw, 512L*4096,  4096, 512);
  cvt(kvb_bf,  kvbw, 2048L*512,  512,  2048);
  cvt(outw_bf, outw, 4096L*1024, 1024, 4096);
  cvt(se_bf,   se,   1024L*4096, 4096, 1000);      // zero-pad rows 1000..1023

  // G1: q_lat = te @ q_a_w^T  (4096x512x1024), split-K2 -> fp32 partials
  gemm_bt<2,2,0,0><<<dim3(4, 32, 2), 256, 0, stream>>>(
      te_bf, 1024, 512, 0, qa_bf, 1024, 512, 0,
      qlat, 512, 4096L*512, 0, nullptr, 4096, 512, 512, 1);
  ln512red<<<4096, 256, 0, stream>>>(qln_bf, qlat, 4096L*512, 2, qlg, qlb, 4096);
  // G2: q = ln(q_lat) @ q_b_w^T  (4096x1024x512), bf16 out
  gemm_bt<2,2,1,0><<<dim3(8, 32, 1), 256, 0, stream>>>(
      qln_bf, 512, 0,0, qb_bf, 512, 0,0, q_bf, 1024, 0,0, nullptr, 4096, 1024, 512, 1);
  // G3: ckv_lat = se @ kv_a_w^T  (1024x512x4096), split-K8 -> fp32 partials
  gemm_bt<2,2,0,0><<<dim3(4, 8, 8), 256, 0, stream>>>(
      se_bf, 4096, 512, 0, kva_bf, 4096, 512, 0,
      ckvp, 512, 1024L*512, 0, nullptr, 1024, 512, 512, 1);
  ln512red<<<1024, 256, 0, stream>>>(ckv_bf, ckvp, 1024L*512, 8, kvlg, kvlb, 1000);
  // G4: kv = ckv @ kv_b_w^T  (1024x2048x512), split-K2 -> fp32 partials
  gemm_bt<2,2,0,0><<<dim3(16, 8, 2), 256, 0, stream>>>(
      ckv_bf, 512, 256, 0, kvb_bf, 512, 256, 0,
      kvf, 2048, 1024L*2048, 0, nullptr, 1024, 2048, 256, 1);
  split_kv<<<dim3(16, 16), 256, 0, stream>>>(kvf, k_bf, vT_bf);

  // Attention in two h-halves of 8 heads; (b,l) folded into M=4096.
  for (int hg = 0; hg < 2; hg++){
    // scores[h][bl][s] = q[bl, h*64:..] . k[h][s][:]   (batch z2 = h in half)
    gemm_bt<2,2,1,0><<<dim3(8, 32, 8), 256, 0, stream>>>(
        q_bf + hg*512, 1024, 0, 64,
        k_bf + (long)hg*8*65536, 64, 0, 65536,
        scores, 1024, 0, 4096L*1024,
        nullptr, 4096, 1024, 64, 8);
    softmax_rows<<<8*4096, 256, 0, stream>>>(scores);
    // attn[bl, h*64+e] = sum_s P[h][bl][s] * vT[h][e][s]
    gemm_bt<2,1,1,0><<<dim3(1, 32, 8), 128, 0, stream>>>(
        scores, 1024, 0, 4096L*1024,
        vT_bf + (long)hg*8*65536, 1024, 0, 65536,
        attn_bf + hg*512, 1024, 0, 64,
        nullptr, 4096, 64, 1024, 8);
  }

  // G7: out = attn @ out_w^T + out_b  (4096x4096x1024), fp32 out + bias
  gemm_bt<2,2,0,1><<<dim3(32, 32, 1), 256, 0, stream>>>(
      attn_bf, 1024, 0,0, outw_bf, 1024, 0,0, out, 4096, 0,0, outb, 4096, 4096, 1024, 1);
}

// Round 4
// 335.396 us; speedup vs baseline: 1.7937x; 1.3293x over previous
//
#include <hip/hip_runtime.h>

typedef unsigned short u16;
typedef __bf16 bf16x8 __attribute__((ext_vector_type(8)));
typedef float f32x4 __attribute__((ext_vector_type(4)));

#define DEV __device__ __forceinline__

DEV u16 f2bf(float f){
  unsigned u = __float_as_uint(f);
  u += 0x7fff + ((u >> 16) & 1);   // round-to-nearest-even
  return (u16)(u >> 16);
}
DEV float bf2f(u16 v){ return __uint_as_float(((unsigned)v) << 16); }

// async global->LDS, 16B per lane. Global addr is PER-LANE; LDS dest is
// wave-uniform base + lane*16 (m104/m108).
DEV void gll16(const void* g, void* l){
  __builtin_amdgcn_global_load_lds(
    (__attribute__((address_space(1))) unsigned int*)(unsigned long long)g,
    (__attribute__((address_space(3))) unsigned int*)(unsigned int)(unsigned long long)l,
    16, 0, 0);
}

// ---------------------------------------------------------------------------
// C[M,N] = A[M,K] @ B[N,K]^T   (bf16 in, fp32 acc, fp32/bf16 out, opt bias)
// ---------------------------------------------------------------------------
template<int WM, int WN, int OBF, int BIAS>
__global__ __launch_bounds__(256) void gemm_bt(
    const u16* __restrict__ A, int lda, long sA1, long sA2,
    const u16* __restrict__ B, int ldb, long sB1, long sB2,
    void* __restrict__ Cv, int ldc, long sC1, long sC2,
    const float* __restrict__ bias,
    int M, int N, int K, int Z2)
{
  constexpr int BM = WM*64, BN = WN*64;
  constexpr int NW = WM*WN;
  constexpr int A_INSTS = BM/16, B_INSTS = BN/16;   // 1024B (16 rows) per inst
  constexpr int APW = A_INSTS/NW, BPW = B_INSTS/NW;
  __shared__ u16 sA[BM*32];
  __shared__ u16 sB[BN*32];
  const int tid  = threadIdx.x;
  const int wave = tid >> 6, lane = tid & 63;
  const int quad = lane >> 4, l16 = lane & 15;
  const int wm = wave % WM, wn = wave / WM;
  const long bm = blockIdx.y, bn = blockIdx.x;
  const int z  = blockIdx.z;
  const int z1 = z / Z2, z2 = z - z1*Z2;
  const u16* Ab = A + z1*sA1 + z2*sA2 + bm*BM*(long)lda;
  const u16* Bb = B + z1*sB1 + z2*sB2 + bn*BN*(long)ldb;

  f32x4 acc[4][4] = {};

  for (int k0 = 0; k0 < K; k0 += 32){
    __syncthreads();
#pragma unroll
    for (int j = 0; j < APW; j++){
      const int inst = wave*APW + j;
      const int o = inst*1024 + lane*16;          // byte offset in 64B-row tile
      const int row = o >> 6, colb = o & 63;
      gll16(Ab + (long)row*lda + k0 + (colb >> 1), &sA[inst*512]);
    }
#pragma unroll
    for (int j = 0; j < BPW; j++){
      const int inst = wave*BPW + j;
      const int o = inst*1024 + lane*16;
      const int row = o >> 6, colb = o & 63;
      gll16(Bb + (long)row*ldb + k0 + (colb >> 1), &sB[inst*512]);
    }
    __syncthreads();
    bf16x8 af[4], bfr[4];
#pragma unroll
    for (int mi = 0; mi < 4; mi++)
      af[mi] = *(const bf16x8*)&sA[(wm*64 + mi*16 + l16)*32 + quad*8];
#pragma unroll
    for (int ni = 0; ni < 4; ni++)
      bfr[ni] = *(const bf16x8*)&sB[(wn*64 + ni*16 + l16)*32 + quad*8];
#pragma unroll
    for (int mi = 0; mi < 4; mi++)
#pragma unroll
      for (int ni = 0; ni < 4; ni++)
        acc[mi][ni] = __builtin_amdgcn_mfma_f32_16x16x32_bf16(af[mi], bfr[ni], acc[mi][ni], 0, 0, 0);
  }

  // C/D layout: row = quad*4 + reg, col = lane&15
  const long crow0 = bm*BM + wm*64 + quad*4;
  const long ccol0 = bn*BN + wn*64 + l16;
  if (OBF){
    u16* Cp = (u16*)Cv + z1*sC1 + z2*sC2;
#pragma unroll
    for (int mi = 0; mi < 4; mi++)
#pragma unroll
      for (int ni = 0; ni < 4; ni++)
#pragma unroll
        for (int r = 0; r < 4; r++)
          Cp[(crow0 + mi*16 + r)*ldc + ccol0 + ni*16] = f2bf(acc[mi][ni][r]);
  } else {
    float* Cp = (float*)Cv + z1*sC1 + z2*sC2;
    float bv[4] = {0.f,0.f,0.f,0.f};
    if (BIAS){
#pragma unroll
      for (int ni = 0; ni < 4; ni++) bv[ni] = bias[ccol0 + ni*16];
    }
#pragma unroll
    for (int mi = 0; mi < 4; mi++)
#pragma unroll
      for (int ni = 0; ni < 4; ni++)
#pragma unroll
        for (int r = 0; r < 4; r++)
          Cp[(crow0 + mi*16 + r)*ldc + ccol0 + ni*16] = acc[mi][ni][r] + bv[ni];
  }
}

// fp32 -> bf16 convert with optional zero row-padding (row >= valid -> 0)
__global__ __launch_bounds__(256) void cvt_bf16(
    u16* __restrict__ dst, const float* __restrict__ src,
    long total, int rowlen, int valid_rows)
{
  long i = ((long)blockIdx.x*256 + threadIdx.x)*4;
  if (i >= total) return;
  long row = i / rowlen;
  ushort4 o;
  if (row < valid_rows){
    float4 v = *(const float4*)(src + i);
    o.x = f2bf(v.x); o.y = f2bf(v.y); o.z = f2bf(v.z); o.w = f2bf(v.w);
  } else { o.x = 0; o.y = 0; o.z = 0; o.w = 0; }
  *(ushort4*)(dst + i) = o;
}

// LayerNorm over rows of 512 with split-K reduction of fp32 partials.
__global__ __launch_bounds__(256) void ln512red(
    u16* __restrict__ out, const float* __restrict__ in, long pstride, int nparts,
    const float* __restrict__ gam, const float* __restrict__ bet, int valid_rows)
{
  const long row = blockIdx.x;
  const int tid = threadIdx.x;
  u16* op = out + row*512 + tid*2;
  if (row >= valid_rows){
    ushort2 z; z.x = 0; z.y = 0;
    *(ushort2*)op = z;
    return;                       // block-uniform branch
  }
  float2 x; x.x = 0.f; x.y = 0.f;
  for (int p = 0; p < nparts; p++){
    float2 v = *(const float2*)(in + p*pstride + row*512 + tid*2);
    x.x += v.x; x.y += v.y;
  }
  float s  = x.x + x.y;
  float s2 = x.x*x.x + x.y*x.y;
#pragma unroll
  for (int m = 32; m; m >>= 1){ s += __shfl_xor(s, m, 64); s2 += __shfl_xor(s2, m, 64); }
  __shared__ float red[8];
  const int wave = tid >> 6, lane = tid & 63;
  if (lane == 0){ red[wave*2] = s; red[wave*2+1] = s2; }
  __syncthreads();
  float ts = red[0]+red[2]+red[4]+red[6];
  float t2 = red[1]+red[3]+red[5]+red[7];
  float mu  = ts * (1.f/512.f);
  float var = t2 * (1.f/512.f) - mu*mu;
  float rs  = rsqrtf(var + 1e-5f);
  float2 g2 = *(const float2*)(gam + tid*2);
  float2 b2 = *(const float2*)(bet + tid*2);
  ushort2 o;
  o.x = f2bf((x.x - mu)*rs*g2.x + b2.x);
  o.y = f2bf((x.y - mu)*rs*g2.y + b2.y);
  *(ushort2*)op = o;
}

// kv partials (2 x [1024 x 2048] fp32) ->
//   kbf[h][s][rot64(e + 8s)]  (bf16, row-rotated for conflict-free frag reads)
//   vT [h][tile][er][rot128(pos + 8*er)] (bf16, transposed + rotated)
__global__ __launch_bounds__(256) void split_kv(
    const float* __restrict__ kv, u16* __restrict__ kbf, u16* __restrict__ vT)
{
  const int h  = blockIdx.x;      // 16
  const int sc = blockIdx.y;      // 16 chunks of 64 s
  const int s0 = sc*64;
  const long PST = 1024L*2048;
  __shared__ u16 tile[64][65];
  const int e  = threadIdx.x & 63;
  const int sg = threadIdx.x >> 6;
#pragma unroll
  for (int i = 0; i < 16; i++){
    const int sl = i*4 + sg;
    const int s = s0 + sl;
    float kvl = kv[(long)s*2048 + h*128 + e]      + kv[PST + (long)s*2048 + h*128 + e];
    float vvl = kv[(long)s*2048 + h*128 + 64 + e] + kv[PST + (long)s*2048 + h*128 + 64 + e];
    kbf[((long)h*1024 + s)*64 + ((e + 8*s) & 63)] = f2bf(kvl);
    tile[sl][e] = f2bf(vvl);
  }
  __syncthreads();
#pragma unroll
  for (int i = 0; i < 16; i++){
    const int er = i*4 + sg;            // e-row 0..63
    const int s  = s0 + e;              // source position
    const int t128 = s >> 7, pos = s & 127;
    vT[(((long)h*8 + t128)*64 + er)*128 + ((pos + 8*er) & 127)] = tile[e][er];
  }
}

// ---------------------------------------------------------------------------
// Fused flash attention. Grid (32 q-tiles, 16 heads), 256 threads (4 waves).
// Q[4096][1024] (head h at col h*64), Kt[h][1024][64] rotated,
// Vt[h][8][64][128] rotated, O[4096][1024].
// S^T orientation: D[m=s][n=q] so softmax(dim=s) reduces in-lane + 2 shuffles.
// ---------------------------------------------------------------------------
__global__ __launch_bounds__(256) void flash_attn(
    const u16* __restrict__ Q, const u16* __restrict__ Kt,
    const u16* __restrict__ Vt, u16* __restrict__ O)
{
  __shared__ u16 sKV[128*64];          // 16 KB: K tile, then V tile (aliased)
  __shared__ u16 sPT[128*136];         // 34 KB: P^T round-trip, [q][s] +8 pad
  __shared__ __align__(16) float sAl[128];
  const int tid = threadIdx.x, w = tid >> 6, lane = tid & 63;
  const int quad = lane >> 4, l16 = lane & 15;
  const int h = blockIdx.y;
  const long q0 = (long)blockIdx.x * 128;

  // Q fragments (B-operand: [n=q][k=e]), kept in registers for all 8 s-tiles
  bf16x8 bq[2][2];
#pragma unroll
  for (int ni = 0; ni < 2; ni++)
#pragma unroll
    for (int kf = 0; kf < 2; kf++)
      bq[ni][kf] = *(const bf16x8*)&Q[(q0 + w*32 + ni*16 + l16)*1024 + h*64 + kf*32 + quad*8];

  f32x4 accO[2][4] = {};
  float mst[2] = {-3e38f, -3e38f};
  float lst[2] = {0.f, 0.f};

  for (int it = 0; it < 8; it++){
    const int s0 = it*128;
    __syncthreads();                               // A: prev-iter LDS reads done
#pragma unroll
    for (int j = 0; j < 4; j++){
      const int inst = w*4 + j;
      gll16(Kt + (long)h*65536 + (long)s0*64 + inst*512 + lane*8, &sKV[inst*512]);
    }
    __syncthreads();                               // B: K tile staged

    // S^T[s][q] = K[s][e] . Q[q][e]
    f32x4 accS[8][2] = {};
#pragma unroll
    for (int kf = 0; kf < 2; kf++)
#pragma unroll
      for (int mi = 0; mi < 8; mi++){
        const int sr = mi*16 + l16;
        bf16x8 ka = *(const bf16x8*)&sKV[sr*64 + ((kf*32 + quad*8 + 8*sr) & 63)];
#pragma unroll
        for (int ni = 0; ni < 2; ni++)
          accS[mi][ni] = __builtin_amdgcn_mfma_f32_16x16x32_bf16(ka, bq[ni][kf], accS[mi][ni], 0, 0, 0);
      }

    // online softmax over s (rows); per lane: 2 q-cols (ni), 32 s each
#pragma unroll
    for (int ni = 0; ni < 2; ni++){
      float tm = -3e38f;
#pragma unroll
      for (int mi = 0; mi < 8; mi++)
#pragma unroll
        for (int r = 0; r < 4; r++){
          float v = accS[mi][ni][r] * 0.125f;
          const int s = s0 + mi*16 + quad*4 + r;
          v = (s < 1000) ? v : -3e38f;
          accS[mi][ni][r] = v;
          tm = fmaxf(tm, v);
        }
      tm = fmaxf(tm, __shfl_xor(tm, 16, 64));
      tm = fmaxf(tm, __shfl_xor(tm, 32, 64));
      const float mnew = fmaxf(mst[ni], tm);
      const float al = __expf(mst[ni] - mnew);
      mst[ni] = mnew;
      float sum = 0.f;
      const int qloc = w*32 + ni*16 + l16;
#pragma unroll
      for (int mi = 0; mi < 8; mi++){
        float p0 = __expf(accS[mi][ni][0] - mnew);
        float p1 = __expf(accS[mi][ni][1] - mnew);
        float p2 = __expf(accS[mi][ni][2] - mnew);
        float p3 = __expf(accS[mi][ni][3] - mnew);
        sum += (p0 + p1) + (p2 + p3);
        ushort4 pk;
        pk.x = f2bf(p0); pk.y = f2bf(p1); pk.z = f2bf(p2); pk.w = f2bf(p3);
        *(ushort4*)&sPT[qloc*136 + mi*16 + quad*4] = pk;   // [q][s] store
      }
      sum += __shfl_xor(sum, 16, 64);
      sum += __shfl_xor(sum, 32, 64);
      lst[ni] = lst[ni]*al + sum;
      if (quad == 0) sAl[qloc] = al;
    }
    __syncthreads();                               // C: sK reads done; sPT,sAl visible
#pragma unroll
    for (int j = 0; j < 4; j++){
      const int inst = w*4 + j;
      gll16(Vt + ((long)(h*8 + it))*8192 + inst*512 + lane*8, &sKV[inst*512]);
    }
    // rescale O by alpha (broadcast read) while V stages
#pragma unroll
    for (int mi = 0; mi < 2; mi++){
      f32x4 al4 = *(const f32x4*)&sAl[w*32 + mi*16 + quad*4];
#pragma unroll
      for (int ni = 0; ni < 4; ni++)
        accO[mi][ni] *= al4;
    }
    __syncthreads();                               // D: V tile staged

    // O[q][e] += P[q][s] . V^T[e][s]
#pragma unroll
    for (int kf = 0; kf < 4; kf++){
      bf16x8 pa[2], vb[4];
#pragma unroll
      for (int mi = 0; mi < 2; mi++)
        pa[mi] = *(const bf16x8*)&sPT[(w*32 + mi*16 + l16)*136 + kf*32 + quad*8];
#pragma unroll
      for (int ni = 0; ni < 4; ni++){
        const int e = ni*16 + l16;
        vb[ni] = *(const bf16x8*)&sKV[e*128 + ((kf*32 + quad*8 + 8*e) & 127)];
      }
#pragma unroll
      for (int mi = 0; mi < 2; mi++)
#pragma unroll
        for (int ni = 0; ni < 4; ni++)
          accO[mi][ni] = __builtin_amdgcn_mfma_f32_16x16x32_bf16(pa[mi], vb[ni], accO[mi][ni], 0, 0, 0);
    }
  }

  __syncthreads();                                 // all alpha reads done
  if (quad == 0){ sAl[w*32 + l16] = lst[0]; sAl[w*32 + 16 + l16] = lst[1]; }
  __syncthreads();
#pragma unroll
  for (int mi = 0; mi < 2; mi++){
    f32x4 l4 = *(const f32x4*)&sAl[w*32 + mi*16 + quad*4];
#pragma unroll
    for (int ni = 0; ni < 4; ni++)
#pragma unroll
      for (int r = 0; r < 4; r++)
        O[(q0 + w*32 + mi*16 + quad*4 + r)*1024 + h*64 + ni*16 + l16] =
            f2bf(accO[mi][ni][r] / l4[r]);
  }
}

extern "C" void kernel_launch(void* const* d_in, const int* in_sizes, int n_in,
                              void* d_out, int out_size, void* d_ws, size_t ws_size,
                              hipStream_t stream)
{
  const float* te   = (const float*)d_in[0];
  const float* se   = (const float*)d_in[1];
  // d_in[2] (value_embedding) is unused by the reference
  const float* qaw  = (const float*)d_in[3];
  const float* qlg  = (const float*)d_in[4];
  const float* qlb  = (const float*)d_in[5];
  const float* qbw  = (const float*)d_in[6];
  const float* kvaw = (const float*)d_in[7];
  const float* kvlg = (const float*)d_in[8];
  const float* kvlb = (const float*)d_in[9];
  const float* kvbw = (const float*)d_in[10];
  const float* outw = (const float*)d_in[11];
  const float* outb = (const float*)d_in[12];
  float* out = (float*)d_out;
  (void)ws_size; (void)in_sizes; (void)n_in; (void)out_size;

  char* ws = (char*)d_ws;
  const size_t MB = 1024*1024;
  u16*   te_bf  = (u16*)  (ws + 0*MB);    // 8MB
  u16*   se_bf  = (u16*)  (ws + 8*MB);    // 8MB
  float* qlat   = (float*)(ws + 16*MB);   // 16MB  G1 partials (2)
  float* ckvp   = (float*)(ws + 32*MB);   // 16MB  G3 partials (8)
  float* kvf    = (float*)(ws + 48*MB);   // 16MB  G4 partials (2)
  u16*   qa_bf   = (u16*)(ws + 64*MB);
  u16*   qb_bf   = (u16*)(ws + 65*MB);
  u16*   kva_bf  = (u16*)(ws + 66*MB);
  u16*   kvb_bf  = (u16*)(ws + 70*MB);
  u16*   outw_bf = (u16*)(ws + 72*MB);
  u16*   qln_bf  = (u16*)(ws + 80*MB);
  u16*   q_bf    = (u16*)(ws + 84*MB);
  u16*   ckv_bf  = (u16*)(ws + 92*MB);
  u16*   k_bf    = (u16*)(ws + 93*MB);    // 2MB  rotated [h][s][64]
  u16*   vT_bf   = (u16*)(ws + 95*MB);    // 2MB  rotated [h][tile][e][128]
  u16*   attn_bf = (u16*)(ws + 97*MB);

  auto cvt = [&](u16* dst, const float* src, long total, int rowlen, int valid){
    int blocks = (int)((total/4 + 255)/256);
    cvt_bf16<<<blocks, 256, 0, stream>>>(dst, src, total, rowlen, valid);
  };
  cvt(te_bf,   te,   4096L*1024, 1024, 4096);
  cvt(qa_bf,   qaw,  512L*1024,  1024, 512);
  cvt(qb_bf,   qbw,  1024L*512,  512,  1024);
  cvt(kva_bf,  kvaw, 512L*4096,  4096, 512);
  cvt(kvb_bf,  kvbw, 2048L*512,  512,  2048);
  cvt(outw_bf, outw, 4096L*1024, 1024, 4096);
  cvt(se_bf,   se,   1024L*4096, 4096, 1000);      // zero-pad rows 1000..1023

  // G1: q_lat = te @ q_a_w^T  (4096x512x1024), split-K2 -> fp32 partials
  gemm_bt<2,2,0,0><<<dim3(4, 32, 2), 256, 0, stream>>>(
      te_bf, 1024, 512, 0, qa_bf, 1024, 512, 0,
      qlat, 512, 4096L*512, 0, nullptr, 4096, 512, 512, 1);
  ln512red<<<4096, 256, 0, stream>>>(qln_bf, qlat, 4096L*512, 2, qlg, qlb, 4096);
  // G2: q = ln(q_lat) @ q_b_w^T  (4096x1024x512), bf16 out
  gemm_bt<2,2,1,0><<<dim3(8, 32, 1), 256, 0, stream>>>(
      qln_bf, 512, 0,0, qb_bf, 512, 0,0, q_bf, 1024, 0,0, nullptr, 4096, 1024, 512, 1);
  // G3: ckv_lat = se @ kv_a_w^T  (1024x512x4096), split-K8 -> fp32 partials
  gemm_bt<2,2,0,0><<<dim3(4, 8, 8), 256, 0, stream>>>(
      se_bf, 4096, 512, 0, kva_bf, 4096, 512, 0,
      ckvp, 512, 1024L*512, 0, nullptr, 1024, 512, 512, 1);
  ln512red<<<1024, 256, 0, stream>>>(ckv_bf, ckvp, 1024L*512, 8, kvlg, kvlb, 1000);
  // G4: kv = ckv @ kv_b_w^T  (1024x2048x512), split-K2 -> fp32 partials
  gemm_bt<2,2,0,0><<<dim3(16, 8, 2), 256, 0, stream>>>(
      ckv_bf, 512, 256, 0, kvb_bf, 512, 256, 0,
      kvf, 2048, 1024L*2048, 0, nullptr, 1024, 2048, 256, 1);
  split_kv<<<dim3(16, 16), 256, 0, stream>>>(kvf, k_bf, vT_bf);

  // Fused attention: one dispatch, 512 blocks
  flash_attn<<<dim3(32, 16), 256, 0, stream>>>(q_bf, k_bf, vT_bf, attn_bf);

  // G7: out = attn @ out_w^T + out_b  (4096x4096x1024), fp32 out + bias
  gemm_bt<2,2,0,1><<<dim3(32, 32, 1), 256, 0, stream>>>(
      attn_bf, 1024, 0,0, outw_bf, 1024, 0,0, out, 4096, 0,0, outb, 4096, 4096, 1024, 1);
}

// Round 5
// 321.830 us; speedup vs baseline: 1.8693x; 1.0422x over previous
//
#include <hip/hip_runtime.h>

typedef unsigned short u16;
typedef __bf16 bf16x8 __attribute__((ext_vector_type(8)));
typedef float f32x4 __attribute__((ext_vector_type(4)));

#define DEV __device__ __forceinline__

DEV u16 f2bf(float f){
  unsigned u = __float_as_uint(f);
  u += 0x7fff + ((u >> 16) & 1);   // round-to-nearest-even
  return (u16)(u >> 16);
}
DEV float bf2f(u16 v){ return __uint_as_float(((unsigned)v) << 16); }

// async global->LDS, 16B per lane. Global addr is PER-LANE; LDS dest is
// wave-uniform base + lane*16 (m104/m108).
DEV void gll16(const void* g, void* l){
  __builtin_amdgcn_global_load_lds(
    (__attribute__((address_space(1))) unsigned int*)(unsigned long long)g,
    (__attribute__((address_space(3))) unsigned int*)(unsigned int)(unsigned long long)l,
    16, 0, 0);
}

// ---------------------------------------------------------------------------
// C[M,N] = A[M,K] @ B[N,K]^T   (bf16 in, fp32 acc, fp32/bf16 out, opt bias)
// ---------------------------------------------------------------------------
template<int WM, int WN, int OBF, int BIAS>
__global__ __launch_bounds__(256) void gemm_bt(
    const u16* __restrict__ A, int lda, long sA1, long sA2,
    const u16* __restrict__ B, int ldb, long sB1, long sB2,
    void* __restrict__ Cv, int ldc, long sC1, long sC2,
    const float* __restrict__ bias,
    int M, int N, int K, int Z2)
{
  constexpr int BM = WM*64, BN = WN*64;
  constexpr int NW = WM*WN;
  constexpr int A_INSTS = BM/16, B_INSTS = BN/16;   // 1024B (16 rows) per inst
  constexpr int APW = A_INSTS/NW, BPW = B_INSTS/NW;
  __shared__ u16 sA[BM*32];
  __shared__ u16 sB[BN*32];
  const int tid  = threadIdx.x;
  const int wave = tid >> 6, lane = tid & 63;
  const int quad = lane >> 4, l16 = lane & 15;
  const int wm = wave % WM, wn = wave / WM;
  const long bm = blockIdx.y, bn = blockIdx.x;
  const int z  = blockIdx.z;
  const int z1 = z / Z2, z2 = z - z1*Z2;
  const u16* Ab = A + z1*sA1 + z2*sA2 + bm*BM*(long)lda;
  const u16* Bb = B + z1*sB1 + z2*sB2 + bn*BN*(long)ldb;

  f32x4 acc[4][4] = {};

  for (int k0 = 0; k0 < K; k0 += 32){
    __syncthreads();
#pragma unroll
    for (int j = 0; j < APW; j++){
      const int inst = wave*APW + j;
      const int o = inst*1024 + lane*16;          // byte offset in 64B-row tile
      const int row = o >> 6, colb = o & 63;
      gll16(Ab + (long)row*lda + k0 + (colb >> 1), &sA[inst*512]);
    }
#pragma unroll
    for (int j = 0; j < BPW; j++){
      const int inst = wave*BPW + j;
      const int o = inst*1024 + lane*16;
      const int row = o >> 6, colb = o & 63;
      gll16(Bb + (long)row*ldb + k0 + (colb >> 1), &sB[inst*512]);
    }
    __syncthreads();
    bf16x8 af[4], bfr[4];
#pragma unroll
    for (int mi = 0; mi < 4; mi++)
      af[mi] = *(const bf16x8*)&sA[(wm*64 + mi*16 + l16)*32 + quad*8];
#pragma unroll
    for (int ni = 0; ni < 4; ni++)
      bfr[ni] = *(const bf16x8*)&sB[(wn*64 + ni*16 + l16)*32 + quad*8];
#pragma unroll
    for (int mi = 0; mi < 4; mi++)
#pragma unroll
      for (int ni = 0; ni < 4; ni++)
        acc[mi][ni] = __builtin_amdgcn_mfma_f32_16x16x32_bf16(af[mi], bfr[ni], acc[mi][ni], 0, 0, 0);
  }

  // C/D layout: row = quad*4 + reg, col = lane&15
  const long crow0 = bm*BM + wm*64 + quad*4;
  const long ccol0 = bn*BN + wn*64 + l16;
  if (OBF){
    u16* Cp = (u16*)Cv + z1*sC1 + z2*sC2;
#pragma unroll
    for (int mi = 0; mi < 4; mi++)
#pragma unroll
      for (int ni = 0; ni < 4; ni++)
#pragma unroll
        for (int r = 0; r < 4; r++)
          Cp[(crow0 + mi*16 + r)*ldc + ccol0 + ni*16] = f2bf(acc[mi][ni][r]);
  } else {
    float* Cp = (float*)Cv + z1*sC1 + z2*sC2;
    float bv[4] = {0.f,0.f,0.f,0.f};
    if (BIAS){
#pragma unroll
      for (int ni = 0; ni < 4; ni++) bv[ni] = bias[ccol0 + ni*16];
    }
#pragma unroll
    for (int mi = 0; mi < 4; mi++)
#pragma unroll
      for (int ni = 0; ni < 4; ni++)
#pragma unroll
        for (int r = 0; r < 4; r++)
          Cp[(crow0 + mi*16 + r)*ldc + ccol0 + ni*16] = acc[mi][ni][r] + bv[ni];
  }
}

// ---------------------------------------------------------------------------
// One launch converting all 7 fp32 arrays to bf16 (se zero-padded past row
// 999). Linear index over groups of 4 elements; segment table hardcoded.
// Total groups: 4,194,304.
// ---------------------------------------------------------------------------
__global__ __launch_bounds__(256) void cvt_all(
    const float* __restrict__ te,   const float* __restrict__ qaw,
    const float* __restrict__ qbw,  const float* __restrict__ kvaw,
    const float* __restrict__ kvbw, const float* __restrict__ outw,
    const float* __restrict__ se,
    u16* __restrict__ te_bf, u16* __restrict__ qa_bf, u16* __restrict__ qb_bf,
    u16* __restrict__ kva_bf, u16* __restrict__ kvb_bf,
    u16* __restrict__ outw_bf, u16* __restrict__ se_bf)
{
  const long NG = 4194304;
  for (long g = (long)blockIdx.x*256 + threadIdx.x; g < NG; g += (long)gridDim.x*256){
    const float* src; u16* dst; long rel; bool zero = false;
    if (g < 1048576)      { src=te;   dst=te_bf;   rel=g; }
    else if (g < 1179648) { src=qaw;  dst=qa_bf;   rel=g-1048576; }
    else if (g < 1310720) { src=qbw;  dst=qb_bf;   rel=g-1179648; }
    else if (g < 1835008) { src=kvaw; dst=kva_bf;  rel=g-1310720; }
    else if (g < 2097152) { src=kvbw; dst=kvb_bf;  rel=g-1835008; }
    else if (g < 3145728) { src=outw; dst=outw_bf; rel=g-2097152; }
    else                  { src=se;   dst=se_bf;   rel=g-3145728; zero = (rel>>10) >= 1000; }
    ushort4 o;
    if (!zero){
      float4 v = *(const float4*)(src + rel*4);
      o.x = f2bf(v.x); o.y = f2bf(v.y); o.z = f2bf(v.z); o.w = f2bf(v.w);
    } else { o.x = 0; o.y = 0; o.z = 0; o.w = 0; }
    *(ushort4*)(dst + rel*4) = o;
  }
}

// ---------------------------------------------------------------------------
// Both LayerNorms in one launch. blocks [0,4096) = q-path (2 partials, all
// rows valid); blocks [4096,5120) = kv-path (8 partials, rows >= 1000 zeroed).
// ---------------------------------------------------------------------------
__global__ __launch_bounds__(256) void ln_both(
    u16* __restrict__ out_q,  const float* __restrict__ in_q,
    const float* __restrict__ qg, const float* __restrict__ qb_,
    u16* __restrict__ out_kv, const float* __restrict__ in_kv,
    const float* __restrict__ kg, const float* __restrict__ kb_)
{
  long row; const float* in; u16* outp; const float* gam; const float* bet;
  int nparts; long pstride; int valid;
  if (blockIdx.x < 4096){
    row = blockIdx.x; in = in_q; outp = out_q; gam = qg; bet = qb_;
    nparts = 2; pstride = 4096L*512; valid = 1;
  } else {
    row = blockIdx.x - 4096; in = in_kv; outp = out_kv; gam = kg; bet = kb_;
    nparts = 8; pstride = 1024L*512; valid = (row < 1000);
  }
  const int tid = threadIdx.x;
  u16* op = outp + row*512 + tid*2;
  if (!valid){
    ushort2 z; z.x = 0; z.y = 0;
    *(ushort2*)op = z;
    return;                       // block-uniform branch
  }
  float2 x; x.x = 0.f; x.y = 0.f;
  for (int p = 0; p < nparts; p++){
    float2 v = *(const float2*)(in + p*pstride + row*512 + tid*2);
    x.x += v.x; x.y += v.y;
  }
  float s  = x.x + x.y;
  float s2 = x.x*x.x + x.y*x.y;
#pragma unroll
  for (int m = 32; m; m >>= 1){ s += __shfl_xor(s, m, 64); s2 += __shfl_xor(s2, m, 64); }
  __shared__ float red[8];
  const int wave = tid >> 6, lane = tid & 63;
  if (lane == 0){ red[wave*2] = s; red[wave*2+1] = s2; }
  __syncthreads();
  float ts = red[0]+red[2]+red[4]+red[6];
  float t2 = red[1]+red[3]+red[5]+red[7];
  float mu  = ts * (1.f/512.f);
  float var = t2 * (1.f/512.f) - mu*mu;
  float rs  = rsqrtf(var + 1e-5f);
  float2 g2 = *(const float2*)(gam + tid*2);
  float2 b2 = *(const float2*)(bet + tid*2);
  ushort2 o;
  o.x = f2bf((x.x - mu)*rs*g2.x + b2.x);
  o.y = f2bf((x.y - mu)*rs*g2.y + b2.y);
  *(ushort2*)op = o;
}

// kv partials (2 x [1024 x 2048] fp32) ->
//   kbf[h][s][rot64(e + 8s)]  (bf16, row-rotated for conflict-free frag reads)
//   vT [h][tile][er][rot128(pos + 8*er)] (bf16, transposed + rotated)
__global__ __launch_bounds__(256) void split_kv(
    const float* __restrict__ kv, u16* __restrict__ kbf, u16* __restrict__ vT)
{
  const int h  = blockIdx.x;      // 16
  const int sc = blockIdx.y;      // 16 chunks of 64 s
  const int s0 = sc*64;
  const long PST = 1024L*2048;
  __shared__ u16 tile[64][65];
  const int e  = threadIdx.x & 63;
  const int sg = threadIdx.x >> 6;
#pragma unroll
  for (int i = 0; i < 16; i++){
    const int sl = i*4 + sg;
    const int s = s0 + sl;
    float kvl = kv[(long)s*2048 + h*128 + e]      + kv[PST + (long)s*2048 + h*128 + e];
    float vvl = kv[(long)s*2048 + h*128 + 64 + e] + kv[PST + (long)s*2048 + h*128 + 64 + e];
    kbf[((long)h*1024 + s)*64 + ((e + 8*s) & 63)] = f2bf(kvl);
    tile[sl][e] = f2bf(vvl);
  }
  __syncthreads();
#pragma unroll
  for (int i = 0; i < 16; i++){
    const int er = i*4 + sg;            // e-row 0..63
    const int s  = s0 + e;              // source position
    const int t128 = s >> 7, pos = s & 127;
    vT[(((long)h*8 + t128)*64 + er)*128 + ((pos + 8*er) & 127)] = tile[e][er];
  }
}

// ---------------------------------------------------------------------------
// Fused flash attention. Grid (32 q-tiles, 16 heads), 256 threads (4 waves).
// ---------------------------------------------------------------------------
__global__ __launch_bounds__(256) void flash_attn(
    const u16* __restrict__ Q, const u16* __restrict__ Kt,
    const u16* __restrict__ Vt, u16* __restrict__ O)
{
  __shared__ u16 sKV[128*64];          // 16 KB: K tile, then V tile (aliased)
  __shared__ u16 sPT[128*136];         // 34 KB: P^T round-trip, [q][s] +8 pad
  __shared__ __align__(16) float sAl[128];
  const int tid = threadIdx.x, w = tid >> 6, lane = tid & 63;
  const int quad = lane >> 4, l16 = lane & 15;
  const int h = blockIdx.y;
  const long q0 = (long)blockIdx.x * 128;

  // Q fragments (B-operand: [n=q][k=e]), kept in registers for all 8 s-tiles
  bf16x8 bq[2][2];
#pragma unroll
  for (int ni = 0; ni < 2; ni++)
#pragma unroll
    for (int kf = 0; kf < 2; kf++)
      bq[ni][kf] = *(const bf16x8*)&Q[(q0 + w*32 + ni*16 + l16)*1024 + h*64 + kf*32 + quad*8];

  f32x4 accO[2][4] = {};
  float mst[2] = {-3e38f, -3e38f};
  float lst[2] = {0.f, 0.f};

  for (int it = 0; it < 8; it++){
    const int s0 = it*128;
    __syncthreads();                               // A: prev-iter LDS reads done
#pragma unroll
    for (int j = 0; j < 4; j++){
      const int inst = w*4 + j;
      gll16(Kt + (long)h*65536 + (long)s0*64 + inst*512 + lane*8, &sKV[inst*512]);
    }
    __syncthreads();                               // B: K tile staged

    // S^T[s][q] = K[s][e] . Q[q][e]
    f32x4 accS[8][2] = {};
#pragma unroll
    for (int kf = 0; kf < 2; kf++)
#pragma unroll
      for (int mi = 0; mi < 8; mi++){
        const int sr = mi*16 + l16;
        bf16x8 ka = *(const bf16x8*)&sKV[sr*64 + ((kf*32 + quad*8 + 8*sr) & 63)];
#pragma unroll
        for (int ni = 0; ni < 2; ni++)
          accS[mi][ni] = __builtin_amdgcn_mfma_f32_16x16x32_bf16(ka, bq[ni][kf], accS[mi][ni], 0, 0, 0);
      }

    // online softmax over s (rows); per lane: 2 q-cols (ni), 32 s each
#pragma unroll
    for (int ni = 0; ni < 2; ni++){
      float tm = -3e38f;
#pragma unroll
      for (int mi = 0; mi < 8; mi++)
#pragma unroll
        for (int r = 0; r < 4; r++){
          float v = accS[mi][ni][r] * 0.125f;
          const int s = s0 + mi*16 + quad*4 + r;
          v = (s < 1000) ? v : -3e38f;
          accS[mi][ni][r] = v;
          tm = fmaxf(tm, v);
        }
      tm = fmaxf(tm, __shfl_xor(tm, 16, 64));
      tm = fmaxf(tm, __shfl_xor(tm, 32, 64));
      const float mnew = fmaxf(mst[ni], tm);
      const float al = __expf(mst[ni] - mnew);
      mst[ni] = mnew;
      float sum = 0.f;
      const int qloc = w*32 + ni*16 + l16;
#pragma unroll
      for (int mi = 0; mi < 8; mi++){
        float p0 = __expf(accS[mi][ni][0] - mnew);
        float p1 = __expf(accS[mi][ni][1] - mnew);
        float p2 = __expf(accS[mi][ni][2] - mnew);
        float p3 = __expf(accS[mi][ni][3] - mnew);
        sum += (p0 + p1) + (p2 + p3);
        ushort4 pk;
        pk.x = f2bf(p0); pk.y = f2bf(p1); pk.z = f2bf(p2); pk.w = f2bf(p3);
        *(ushort4*)&sPT[qloc*136 + mi*16 + quad*4] = pk;   // [q][s] store
      }
      sum += __shfl_xor(sum, 16, 64);
      sum += __shfl_xor(sum, 32, 64);
      lst[ni] = lst[ni]*al + sum;
      if (quad == 0) sAl[qloc] = al;
    }
    __syncthreads();                               // C: sK reads done; sPT,sAl visible
#pragma unroll
    for (int j = 0; j < 4; j++){
      const int inst = w*4 + j;
      gll16(Vt + ((long)(h*8 + it))*8192 + inst*512 + lane*8, &sKV[inst*512]);
    }
    // rescale O by alpha (broadcast read) while V stages
#pragma unroll
    for (int mi = 0; mi < 2; mi++){
      f32x4 al4 = *(const f32x4*)&sAl[w*32 + mi*16 + quad*4];
#pragma unroll
      for (int ni = 0; ni < 4; ni++)
        accO[mi][ni] *= al4;
    }
    __syncthreads();                               // D: V tile staged

    // O[q][e] += P[q][s] . V^T[e][s]
#pragma unroll
    for (int kf = 0; kf < 4; kf++){
      bf16x8 pa[2], vb[4];
#pragma unroll
      for (int mi = 0; mi < 2; mi++)
        pa[mi] = *(const bf16x8*)&sPT[(w*32 + mi*16 + l16)*136 + kf*32 + quad*8];
#pragma unroll
      for (int ni = 0; ni < 4; ni++){
        const int e = ni*16 + l16;
        vb[ni] = *(const bf16x8*)&sKV[e*128 + ((kf*32 + quad*8 + 8*e) & 127)];
      }
#pragma unroll
      for (int mi = 0; mi < 2; mi++)
#pragma unroll
        for (int ni = 0; ni < 4; ni++)
          accO[mi][ni] = __builtin_amdgcn_mfma_f32_16x16x32_bf16(pa[mi], vb[ni], accO[mi][ni], 0, 0, 0);
    }
  }

  __syncthreads();                                 // all alpha reads done
  if (quad == 0){ sAl[w*32 + l16] = lst[0]; sAl[w*32 + 16 + l16] = lst[1]; }
  __syncthreads();
#pragma unroll
  for (int mi = 0; mi < 2; mi++){
    f32x4 l4 = *(const f32x4*)&sAl[w*32 + mi*16 + quad*4];
#pragma unroll
    for (int ni = 0; ni < 4; ni++)
#pragma unroll
      for (int r = 0; r < 4; r++)
        O[(q0 + w*32 + mi*16 + quad*4 + r)*1024 + h*64 + ni*16 + l16] =
            f2bf(accO[mi][ni][r] / l4[r]);
  }
}

extern "C" void kernel_launch(void* const* d_in, const int* in_sizes, int n_in,
                              void* d_out, int out_size, void* d_ws, size_t ws_size,
                              hipStream_t stream)
{
  const float* te   = (const float*)d_in[0];
  const float* se   = (const float*)d_in[1];
  // d_in[2] (value_embedding) is unused by the reference
  const float* qaw  = (const float*)d_in[3];
  const float* qlg  = (const float*)d_in[4];
  const float* qlb  = (const float*)d_in[5];
  const float* qbw  = (const float*)d_in[6];
  const float* kvaw = (const float*)d_in[7];
  const float* kvlg = (const float*)d_in[8];
  const float* kvlb = (const float*)d_in[9];
  const float* kvbw = (const float*)d_in[10];
  const float* outw = (const float*)d_in[11];
  const float* outb = (const float*)d_in[12];
  float* out = (float*)d_out;
  (void)ws_size; (void)in_sizes; (void)n_in; (void)out_size;

  char* ws = (char*)d_ws;
  const size_t MB = 1024*1024;
  u16*   te_bf  = (u16*)  (ws + 0*MB);    // 8MB
  u16*   se_bf  = (u16*)  (ws + 8*MB);    // 8MB
  float* qlat   = (float*)(ws + 16*MB);   // 16MB  G1 partials (2)
  float* ckvp   = (float*)(ws + 32*MB);   // 16MB  G3 partials (8)
  float* kvf    = (float*)(ws + 48*MB);   // 16MB  G4 partials (2)
  u16*   qa_bf   = (u16*)(ws + 64*MB);
  u16*   qb_bf   = (u16*)(ws + 65*MB);
  u16*   kva_bf  = (u16*)(ws + 66*MB);
  u16*   kvb_bf  = (u16*)(ws + 70*MB);
  u16*   outw_bf = (u16*)(ws + 72*MB);
  u16*   qln_bf  = (u16*)(ws + 80*MB);
  u16*   q_bf    = (u16*)(ws + 84*MB);
  u16*   ckv_bf  = (u16*)(ws + 92*MB);
  u16*   k_bf    = (u16*)(ws + 93*MB);    // 2MB  rotated [h][s][64]
  u16*   vT_bf   = (u16*)(ws + 95*MB);    // 2MB  rotated [h][tile][e][128]
  u16*   attn_bf = (u16*)(ws + 97*MB);

  // 1 launch: all fp32->bf16 conversions (se zero-padded to 1024 rows)
  cvt_all<<<4096, 256, 0, stream>>>(
      te, qaw, qbw, kvaw, kvbw, outw, se,
      te_bf, qa_bf, qb_bf, kva_bf, kvb_bf, outw_bf, se_bf);

  // G1: q_lat = te @ q_a_w^T  (4096x512x1024), split-K2 -> fp32 partials
  gemm_bt<2,2,0,0><<<dim3(4, 32, 2), 256, 0, stream>>>(
      te_bf, 1024, 512, 0, qa_bf, 1024, 512, 0,
      qlat, 512, 4096L*512, 0, nullptr, 4096, 512, 512, 1);
  // G3: ckv_lat = se @ kv_a_w^T  (1024x512x4096), split-K8 -> fp32 partials
  gemm_bt<2,2,0,0><<<dim3(4, 8, 8), 256, 0, stream>>>(
      se_bf, 4096, 512, 0, kva_bf, 4096, 512, 0,
      ckvp, 512, 1024L*512, 0, nullptr, 1024, 512, 512, 1);
  // Both LayerNorms in one launch
  ln_both<<<4096 + 1024, 256, 0, stream>>>(
      qln_bf, qlat, qlg, qlb, ckv_bf, ckvp, kvlg, kvlb);
  // G2: q = ln(q_lat) @ q_b_w^T  (4096x1024x512), bf16 out
  gemm_bt<2,2,1,0><<<dim3(8, 32, 1), 256, 0, stream>>>(
      qln_bf, 512, 0,0, qb_bf, 512, 0,0, q_bf, 1024, 0,0, nullptr, 4096, 1024, 512, 1);
  // G4: kv = ckv @ kv_b_w^T  (1024x2048x512), split-K2 -> fp32 partials
  gemm_bt<2,2,0,0><<<dim3(16, 8, 2), 256, 0, stream>>>(
      ckv_bf, 512, 256, 0, kvb_bf, 512, 256, 0,
      kvf, 2048, 1024L*2048, 0, nullptr, 1024, 2048, 256, 1);
  split_kv<<<dim3(16, 16), 256, 0, stream>>>(kvf, k_bf, vT_bf);

  // Fused attention: one dispatch, 512 blocks
  flash_attn<<<dim3(32, 16), 256, 0, stream>>>(q_bf, k_bf, vT_bf, attn_bf);

  // G7: out = attn @ out_w^T + out_b  (4096x4096x1024), fp32 out + bias
  gemm_bt<2,2,0,1><<<dim3(32, 32, 1), 256, 0, stream>>>(
      attn_bf, 1024, 0,0, outw_bf, 1024, 0,0, out, 4096, 0,0, outb, 4096, 4096, 1024, 1);
}